// Round 3
// baseline (2783.277 us; speedup 1.0000x reference)
//
#include <hip/hip_runtime.h>
#include <hip/hip_bf16.h>

#define N_NODES 200000
#define N_EDGES 600000
#define NODE_IN 32
#define EDGE_IN 16
#define HID     128
#define LN_EPS  1e-5f

// -------------------- node encoder: h = x @ enc_w + enc_b --------------------
__global__ __launch_bounds__(256) void k_node_enc(
    const float* __restrict__ x, const float* __restrict__ w,
    const float* __restrict__ b, float* __restrict__ h)
{
    __shared__ float sx[16][NODE_IN];           // 2 KB
    const int tid = threadIdx.x;
    const int n0  = blockIdx.x * 16;
    float* sxf = &sx[0][0];
    sxf[tid]       = x[(size_t)n0 * NODE_IN + tid];
    sxf[tid + 256] = x[(size_t)n0 * NODE_IN + tid + 256];

    const int f   = tid & 127;
    const int grp = tid >> 7;                   // 0..1
    float wcol[NODE_IN];
#pragma unroll
    for (int k = 0; k < NODE_IN; k++) wcol[k] = w[k * HID + f];
    const float bf = b[f];
    __syncthreads();

#pragma unroll
    for (int it = 0; it < 8; it++) {
        const int ln = it * 2 + grp;
        const int n  = n0 + ln;
        const float4* sx4 = (const float4*)sx[ln];
        float acc = bf;
#pragma unroll
        for (int k4 = 0; k4 < NODE_IN / 4; k4++) {
            float4 v = sx4[k4];
            acc += v.x * wcol[k4*4] + v.y * wcol[k4*4+1] +
                   v.z * wcol[k4*4+2] + v.w * wcol[k4*4+3];
        }
        h[(size_t)n * HID + f] = acc;
    }
}

// ---------- init: buf = (1+eps)*h (elementwise), zero LN reduction slots ----------
__global__ __launch_bounds__(256) void k_scale_init(
    const float* __restrict__ h, const float* __restrict__ epsp,
    float* __restrict__ buf, float* __restrict__ red)
{
    const float alpha = 1.0f + epsp[0];
    const int i = blockIdx.x * 256 + threadIdx.x;      // exactly NH/4 float4
    float4 v = ((const float4*)h)[i];
    v.x *= alpha; v.y *= alpha; v.z *= alpha; v.w *= alpha;
    ((float4*)buf)[i] = v;
    if (blockIdx.x == 0 && threadIdx.x == 0) { red[0] = 0.f; red[1] = 0.f; }
}

// ---------- message + scatter: buf[dst] += relu(h[src] + e), e recomputed ----------
__global__ __launch_bounds__(256) void k_msg(
    const float* __restrict__ h, const int* __restrict__ ei,
    const float* __restrict__ ea, const float* __restrict__ eew,
    const float* __restrict__ eeb, float* __restrict__ buf)
{
    __shared__ float sea[16][EDGE_IN];          // 1 KB
    const int* __restrict__ src = ei;
    const int* __restrict__ dst = ei + N_EDGES;
    const int tid = threadIdx.x;
    const int e0  = blockIdx.x * 16;
    ((float*)sea)[tid] = ea[(size_t)e0 * EDGE_IN + tid];   // 16 edges x 16 feats

    const int f   = tid & 127;
    const int grp = tid >> 7;
    float wcol[EDGE_IN];
#pragma unroll
    for (int k = 0; k < EDGE_IN; k++) wcol[k] = eew[k * HID + f];
    const float bf = eeb[f];
    __syncthreads();

#pragma unroll
    for (int it = 0; it < 8; it++) {
        const int le = it * 2 + grp;
        const int e  = e0 + le;
        const int s  = src[e];
        const int d  = dst[e];
        const float4* se4 = (const float4*)sea[le];
        float ev = bf;
#pragma unroll
        for (int k4 = 0; k4 < EDGE_IN / 4; k4++) {
            float4 v = se4[k4];
            ev += v.x * wcol[k4*4] + v.y * wcol[k4*4+1] +
                  v.z * wcol[k4*4+2] + v.w * wcol[k4*4+3];
        }
        float m = h[(size_t)s * HID + f] + ev;
        m = fmaxf(m, 0.f);
        atomicAdd(&buf[(size_t)d * HID + f], m);
    }
}

// -------------------- GEMM [M x 128] @ [128 x 128] + bias (IN-PLACE SAFE) ----
// Each block stages its own 64 rows into LDS before writing the same rows, so
// in == out is legal (hence no __restrict__ on in/out).
// RELU_OUT: relu epilogue. REDUCE: accumulate sum/sumsq into red[0..1].
template<bool RELU_OUT, bool REDUCE>
__global__ __launch_bounds__(256) void k_gemm(
    const float* in, const float* __restrict__ W,
    const float* __restrict__ bias, float* out,
    float* __restrict__ red)
{
    __shared__ float sZ[64][HID];               // 32 KB
    const int tid = threadIdx.x;
    const int m0  = blockIdx.x * 64;

    const float4* in4 = (const float4*)(in + (size_t)m0 * HID);
    float4* sZ4 = (float4*)&sZ[0][0];
#pragma unroll
    for (int it = 0; it < 8; it++) {
        const int q = it * 256 + tid;
        sZ4[q] = in4[q];
    }
    __syncthreads();

    const int nt = tid & 31;                    // n = nt*4 .. nt*4+3
    const int mt = tid >> 5;                    // rows mt*8 .. mt*8+7
    float acc[8][4] = {};
    const float4* Wg = (const float4*)W;        // W[k][n], row = 32 float4
    for (int k4 = 0; k4 < 32; k4++) {
        float4 w0 = Wg[(k4*4 + 0) * 32 + nt];
        float4 w1 = Wg[(k4*4 + 1) * 32 + nt];
        float4 w2 = Wg[(k4*4 + 2) * 32 + nt];
        float4 w3 = Wg[(k4*4 + 3) * 32 + nt];
#pragma unroll
        for (int i = 0; i < 8; i++) {
            float4 z = *(const float4*)&sZ[mt*8 + i][k4*4];
            acc[i][0] += z.x*w0.x + z.y*w1.x + z.z*w2.x + z.w*w3.x;
            acc[i][1] += z.x*w0.y + z.y*w1.y + z.z*w2.y + z.w*w3.y;
            acc[i][2] += z.x*w0.z + z.y*w1.z + z.z*w2.z + z.w*w3.z;
            acc[i][3] += z.x*w0.w + z.y*w1.w + z.z*w2.w + z.w*w3.w;
        }
    }

    float4 bv = ((const float4*)bias)[nt];
    float lsum = 0.f, lsq = 0.f;
    float4* out4 = (float4*)(out + (size_t)m0 * HID);
#pragma unroll
    for (int i = 0; i < 8; i++) {
        float4 o;
        o.x = acc[i][0] + bv.x; o.y = acc[i][1] + bv.y;
        o.z = acc[i][2] + bv.z; o.w = acc[i][3] + bv.w;
        if constexpr (RELU_OUT) {
            o.x = fmaxf(o.x, 0.f); o.y = fmaxf(o.y, 0.f);
            o.z = fmaxf(o.z, 0.f); o.w = fmaxf(o.w, 0.f);
        }
        if constexpr (REDUCE) {
            lsum += o.x + o.y + o.z + o.w;
            lsq  += o.x*o.x + o.y*o.y + o.z*o.z + o.w*o.w;
        }
        out4[(size_t)(mt*8 + i) * 32 + nt] = o;
    }

    if constexpr (REDUCE) {
#pragma unroll
        for (int off = 32; off; off >>= 1) {
            lsum += __shfl_down(lsum, off);
            lsq  += __shfl_down(lsq, off);
        }
        __shared__ float sws[4], swq[4];
        const int lane = tid & 63, wid = tid >> 6;
        if (lane == 0) { sws[wid] = lsum; swq[wid] = lsq; }
        __syncthreads();
        if (tid == 0) {
            atomicAdd(&red[0], sws[0] + sws[1] + sws[2] + sws[3]);
            atomicAdd(&red[1], swq[0] + swq[1] + swq[2] + swq[3]);
        }
    }
}

// -------------------- LN finalize: mu, rstd from sums --------------------
__global__ void k_lnfin(float* __restrict__ red)
{
    if (threadIdx.x == 0) {
        const float inv = 1.0f / ((float)N_NODES * (float)HID);
        const float mu  = red[0] * inv;
        const float var = red[1] * inv - mu * mu;
        red[2] = mu;
        red[3] = 1.0f / sqrtf(var + LN_EPS);
    }
}

// ---------- LN apply + relu: h = relu((z - mu)*rstd*g + b) ----------
__global__ __launch_bounds__(256) void k_ln(
    const float* __restrict__ z, const float* __restrict__ red,
    const float* __restrict__ g, const float* __restrict__ b,
    float* __restrict__ hout)
{
    const float mu = red[2], rstd = red[3];
    const int i = blockIdx.x * 256 + threadIdx.x;    // exactly NH/4 float4
    float4 v  = ((const float4*)z)[i];
    float4 gv = ((const float4*)g)[i & 31];
    float4 bv = ((const float4*)b)[i & 31];
    float4 o;
    o.x = fmaxf((v.x - mu) * rstd * gv.x + bv.x, 0.f);
    o.y = fmaxf((v.y - mu) * rstd * gv.y + bv.y, 0.f);
    o.z = fmaxf((v.z - mu) * rstd * gv.z + bv.z, 0.f);
    o.w = fmaxf((v.w - mu) * rstd * gv.w + bv.w, 0.f);
    ((float4*)hout)[i] = o;
}

// ---------- final MLP: logits = relu([h_src,h_dst,e] @ w1 + b1) @ w2 + b2 ----------
__global__ __launch_bounds__(256) void k_mlp(
    const float* __restrict__ h, const int* __restrict__ ei,
    const float* __restrict__ ea, const float* __restrict__ eew,
    const float* __restrict__ eeb,
    const float* __restrict__ w1, const float* __restrict__ b1,
    const float* __restrict__ w2, const float* __restrict__ b2,
    float* __restrict__ out)
{
    __shared__ float sin_[32][384];             // 48 KB
    __shared__ float sea[32][EDGE_IN];          // 2 KB
    const int* __restrict__ src = ei;
    const int* __restrict__ dst = ei + N_EDGES;
    const int tid = threadIdx.x;
    const int e0  = blockIdx.x * 32;

    {
        const float* base = ea + (size_t)e0 * EDGE_IN;
        ((float*)sea)[tid]       = base[tid];
        ((float*)sea)[tid + 256] = base[tid + 256];
    }
    const float4* h4 = (const float4*)h;
#pragma unroll
    for (int it = 0; it < 8; it++) {
        const int q  = it * 256 + tid;
        const int e  = q >> 6;
        const int c4 = q & 63;
        const int node = (c4 < 32) ? src[e0 + e] : dst[e0 + e];
        ((float4*)&sin_[e][0])[c4] = h4[(size_t)node * 32 + (c4 & 31)];
    }
    __syncthreads();

    {
        const int f = tid & 127;
        float wcol[EDGE_IN];
#pragma unroll
        for (int k = 0; k < EDGE_IN; k++) wcol[k] = eew[k * HID + f];
        const float bf = eeb[f];
#pragma unroll
        for (int it = 0; it < 16; it++) {
            const int e = it * 2 + (tid >> 7);
            const float4* se4 = (const float4*)sea[e];
            float ev = bf;
#pragma unroll
            for (int k4 = 0; k4 < EDGE_IN / 4; k4++) {
                float4 v = se4[k4];
                ev += v.x * wcol[k4*4] + v.y * wcol[k4*4+1] +
                      v.z * wcol[k4*4+2] + v.w * wcol[k4*4+3];
            }
            sin_[e][256 + f] = ev;
        }
    }
    __syncthreads();

    const int kt = tid & 31;                    // hidden cols kt*4..+3
    const int eg = tid >> 5;                    // edges eg*4..+3
    float acc[4][4] = {};
    const float4* w14 = (const float4*)w1;      // [384][32 float4]
    for (int j4 = 0; j4 < 96; j4++) {
        float4 w0  = w14[(size_t)(j4*4 + 0) * 32 + kt];
        float4 w1v = w14[(size_t)(j4*4 + 1) * 32 + kt];
        float4 w2v = w14[(size_t)(j4*4 + 2) * 32 + kt];
        float4 w3  = w14[(size_t)(j4*4 + 3) * 32 + kt];
#pragma unroll
        for (int i = 0; i < 4; i++) {
            float4 z = *(const float4*)&sin_[eg*4 + i][j4*4];
            acc[i][0] += z.x*w0.x + z.y*w1v.x + z.z*w2v.x + z.w*w3.x;
            acc[i][1] += z.x*w0.y + z.y*w1v.y + z.z*w2v.y + z.w*w3.y;
            acc[i][2] += z.x*w0.z + z.y*w1v.z + z.z*w2v.z + z.w*w3.z;
            acc[i][3] += z.x*w0.w + z.y*w1v.w + z.z*w2v.w + z.w*w3.w;
        }
    }

    float4 b1v = ((const float4*)b1)[kt];
    float4 w2c = ((const float4*)w2)[kt];
    float part[4];
#pragma unroll
    for (int i = 0; i < 4; i++) {
        float hx = fmaxf(acc[i][0] + b1v.x, 0.f);
        float hy = fmaxf(acc[i][1] + b1v.y, 0.f);
        float hz = fmaxf(acc[i][2] + b1v.z, 0.f);
        float hw = fmaxf(acc[i][3] + b1v.w, 0.f);
        part[i] = hx*w2c.x + hy*w2c.y + hz*w2c.z + hw*w2c.w;
    }
#pragma unroll
    for (int m = 16; m; m >>= 1) {
#pragma unroll
        for (int i = 0; i < 4; i++) part[i] += __shfl_xor(part[i], m);
    }
    if (kt == 0) {
        const float bb = b2[0];
#pragma unroll
        for (int i = 0; i < 4; i++) out[e0 + eg*4 + i] = part[i] + bb;
    }
}

// ------------------------------------------------------------------
extern "C" void kernel_launch(void* const* d_in, const int* in_sizes, int n_in,
                              void* d_out, int out_size, void* d_ws, size_t ws_size,
                              hipStream_t stream)
{
    const float* x    = (const float*)d_in[0];
    const int*   ei   = (const int*)  d_in[1];
    const float* ea   = (const float*)d_in[2];
    const float* encw = (const float*)d_in[3];
    const float* encb = (const float*)d_in[4];
    const float* eew  = (const float*)d_in[5];
    const float* eeb  = (const float*)d_in[6];
    const float* gw1  = (const float*)d_in[7];
    const float* gb1  = (const float*)d_in[8];
    const float* gw2  = (const float*)d_in[9];
    const float* gb2  = (const float*)d_in[10];
    const float* geps = (const float*)d_in[11];
    const float* lng  = (const float*)d_in[12];
    const float* lnb  = (const float*)d_in[13];
    const float* mw1  = (const float*)d_in[14];
    const float* mb1  = (const float*)d_in[15];
    const float* mw2  = (const float*)d_in[16];
    const float* mb2  = (const float*)d_in[17];

    float* ws = (float*)d_ws;
    const size_t NH = (size_t)N_NODES * HID;    // 25,600,000 floats
    float* h    = ws;                           // node state
    float* buf  = ws + NH;                      // agg -> z1 -> z2 (in-place gemms)
    float* red  = ws + 2 * NH;                  // [sum, sumsq, mu, rstd]
    // total d_ws usage: (2*NH + 4) * 4 bytes = 204,800,016 B

    k_node_enc<<<N_NODES / 16, 256, 0, stream>>>(x, encw, encb, h);

    const int ELEM_BLKS = (int)(NH / 4 / 256);  // 25000
    for (int l = 0; l < 3; l++) {
        k_scale_init<<<ELEM_BLKS, 256, 0, stream>>>(h, geps + l, buf, red);
        k_msg<<<N_EDGES / 16, 256, 0, stream>>>(h, ei, ea, eew, eeb, buf);
        k_gemm<true, false><<<N_NODES / 64, 256, 0, stream>>>(
            buf, gw1 + (size_t)l * HID * HID, gb1 + (size_t)l * HID, buf, nullptr);
        k_gemm<false, true><<<N_NODES / 64, 256, 0, stream>>>(
            buf, gw2 + (size_t)l * HID * HID, gb2 + (size_t)l * HID, buf, red);
        k_lnfin<<<1, 64, 0, stream>>>(red);
        k_ln<<<ELEM_BLKS, 256, 0, stream>>>(
            buf, red, lng + (size_t)l * HID, lnb + (size_t)l * HID, h);
    }

    k_mlp<<<N_EDGES / 32, 256, 0, stream>>>(h, ei, ea, eew, eeb,
                                            mw1, mb1, mw2, mb2, (float*)d_out);
}

// Round 6
// 1950.902 us; speedup vs baseline: 1.4267x; 1.4267x over previous
//
#include <hip/hip_runtime.h>
#include <hip/hip_bf16.h>

#define N_NODES 200000
#define N_EDGES 600000
#define NODE_IN 32
#define EDGE_IN 16
#define HID     128
#define LN_EPS  1e-5f

typedef __attribute__((ext_vector_type(8))) short short8;   // 8 bf16 (4 VGPRs)
typedef __attribute__((ext_vector_type(4))) float f32x4;    // MFMA C/D frag

// fp32 -> bf16 round-to-nearest-even (finite values)
static __device__ __forceinline__ ushort f2b(float f) {
    unsigned u = __builtin_bit_cast(unsigned, f);
    unsigned r = (u + 0x7fffu + ((u >> 16) & 1u)) >> 16;
    return (ushort)r;
}

// ---- node encoder: h = x @ enc_w + enc_b ; also buf = (1+eps0)*h, zero red ----
__global__ __launch_bounds__(256) void k_node_enc(
    const float* __restrict__ x, const float* __restrict__ w,
    const float* __restrict__ b, float* __restrict__ h,
    const float* __restrict__ epsp, float* __restrict__ buf,
    float* __restrict__ red)
{
    __shared__ float sx[16][NODE_IN];           // 2 KB
    const int tid = threadIdx.x;
    const int n0  = blockIdx.x * 16;
    float* sxf = &sx[0][0];
    sxf[tid]       = x[(size_t)n0 * NODE_IN + tid];
    sxf[tid + 256] = x[(size_t)n0 * NODE_IN + tid + 256];

    const int f   = tid & 127;
    const int grp = tid >> 7;                   // 0..1
    float wcol[NODE_IN];
#pragma unroll
    for (int k = 0; k < NODE_IN; k++) wcol[k] = w[k * HID + f];
    const float bf = b[f];
    const float alpha = 1.0f + epsp[0];
    __syncthreads();

#pragma unroll
    for (int it = 0; it < 8; it++) {
        const int ln = it * 2 + grp;
        const int n  = n0 + ln;
        const float4* sx4 = (const float4*)sx[ln];
        float acc = bf;
#pragma unroll
        for (int k4 = 0; k4 < NODE_IN / 4; k4++) {
            float4 v = sx4[k4];
            acc += v.x * wcol[k4*4] + v.y * wcol[k4*4+1] +
                   v.z * wcol[k4*4+2] + v.w * wcol[k4*4+3];
        }
        h[(size_t)n * HID + f]   = acc;
        buf[(size_t)n * HID + f] = alpha * acc;
    }
    if (blockIdx.x == 0 && tid == 0) { red[0] = 0.f; red[1] = 0.f; }
}

// ---------- message + scatter: buf[dst] += relu(h[src] + e), e recomputed ----------
__global__ __launch_bounds__(256) void k_msg(
    const float* __restrict__ h, const int* __restrict__ ei,
    const float* __restrict__ ea, const float* __restrict__ eew,
    const float* __restrict__ eeb, float* __restrict__ buf)
{
    __shared__ float sea[16][EDGE_IN];          // 1 KB
    const int* __restrict__ src = ei;
    const int* __restrict__ dst = ei + N_EDGES;
    const int tid = threadIdx.x;
    const int e0  = blockIdx.x * 16;
    ((float*)sea)[tid] = ea[(size_t)e0 * EDGE_IN + tid];   // 16 edges x 16 feats

    const int f   = tid & 127;
    const int grp = tid >> 7;
    float wcol[EDGE_IN];
#pragma unroll
    for (int k = 0; k < EDGE_IN; k++) wcol[k] = eew[k * HID + f];
    const float bf = eeb[f];
    __syncthreads();

#pragma unroll
    for (int it = 0; it < 8; it++) {
        const int le = it * 2 + grp;
        const int e  = e0 + le;
        const int s  = src[e];
        const int d  = dst[e];
        const float4* se4 = (const float4*)sea[le];
        float ev = bf;
#pragma unroll
        for (int k4 = 0; k4 < EDGE_IN / 4; k4++) {
            float4 v = se4[k4];
            ev += v.x * wcol[k4*4] + v.y * wcol[k4*4+1] +
                  v.z * wcol[k4*4+2] + v.w * wcol[k4*4+3];
        }
        float m = h[(size_t)s * HID + f] + ev;
        m = fmaxf(m, 0.f);
        atomicAdd(&buf[(size_t)d * HID + f], m);
    }
}

// -------------------- GEMM [M x 128] @ [128 x 128] + bias (IN-PLACE SAFE) ----
template<bool RELU_OUT, bool REDUCE>
__global__ __launch_bounds__(256) void k_gemm(
    const float* in, const float* __restrict__ W,
    const float* __restrict__ bias, float* out,
    float* __restrict__ red)
{
    __shared__ float sZ[64][HID];               // 32 KB
    const int tid = threadIdx.x;
    const int m0  = blockIdx.x * 64;

    const float4* in4 = (const float4*)(in + (size_t)m0 * HID);
    float4* sZ4 = (float4*)&sZ[0][0];
#pragma unroll
    for (int it = 0; it < 8; it++) {
        const int q = it * 256 + tid;
        sZ4[q] = in4[q];
    }
    __syncthreads();

    const int nt = tid & 31;                    // n = nt*4 .. nt*4+3
    const int mt = tid >> 5;                    // rows mt*8 .. mt*8+7
    float acc[8][4] = {};
    const float4* Wg = (const float4*)W;        // W[k][n], row = 32 float4
    for (int k4 = 0; k4 < 32; k4++) {
        float4 w0 = Wg[(k4*4 + 0) * 32 + nt];
        float4 w1 = Wg[(k4*4 + 1) * 32 + nt];
        float4 w2 = Wg[(k4*4 + 2) * 32 + nt];
        float4 w3 = Wg[(k4*4 + 3) * 32 + nt];
#pragma unroll
        for (int i = 0; i < 8; i++) {
            float4 z = *(const float4*)&sZ[mt*8 + i][k4*4];
            acc[i][0] += z.x*w0.x + z.y*w1.x + z.z*w2.x + z.w*w3.x;
            acc[i][1] += z.x*w0.y + z.y*w1.y + z.z*w2.y + z.w*w3.y;
            acc[i][2] += z.x*w0.z + z.y*w1.z + z.z*w2.z + z.w*w3.z;
            acc[i][3] += z.x*w0.w + z.y*w1.w + z.z*w2.w + z.w*w3.w;
        }
    }

    float4 bv = ((const float4*)bias)[nt];
    float lsum = 0.f, lsq = 0.f;
    float4* out4 = (float4*)(out + (size_t)m0 * HID);
#pragma unroll
    for (int i = 0; i < 8; i++) {
        float4 o;
        o.x = acc[i][0] + bv.x; o.y = acc[i][1] + bv.y;
        o.z = acc[i][2] + bv.z; o.w = acc[i][3] + bv.w;
        if constexpr (RELU_OUT) {
            o.x = fmaxf(o.x, 0.f); o.y = fmaxf(o.y, 0.f);
            o.z = fmaxf(o.z, 0.f); o.w = fmaxf(o.w, 0.f);
        }
        if constexpr (REDUCE) {
            lsum += o.x + o.y + o.z + o.w;
            lsq  += o.x*o.x + o.y*o.y + o.z*o.z + o.w*o.w;
        }
        out4[(size_t)(mt*8 + i) * 32 + nt] = o;
    }

    if constexpr (REDUCE) {
#pragma unroll
        for (int off = 32; off; off >>= 1) {
            lsum += __shfl_down(lsum, off);
            lsq  += __shfl_down(lsq, off);
        }
        __shared__ float sws[4], swq[4];
        const int lane = tid & 63, wid = tid >> 6;
        if (lane == 0) { sws[wid] = lsum; swq[wid] = lsq; }
        __syncthreads();
        if (tid == 0) {
            atomicAdd(&red[0], sws[0] + sws[1] + sws[2] + sws[3]);
            atomicAdd(&red[1], swq[0] + swq[1] + swq[2] + swq[3]);
        }
    }
}

// ---- LN finalize: mu, rstd from sums; re-zero accumulators for next layer ----
__global__ void k_lnfin(float* __restrict__ red)
{
    if (threadIdx.x == 0) {
        const float inv = 1.0f / ((float)N_NODES * (float)HID);
        const float mu  = red[0] * inv;
        const float var = red[1] * inv - mu * mu;
        red[2] = mu;
        red[3] = 1.0f / sqrtf(var + LN_EPS);
        red[0] = 0.f; red[1] = 0.f;
    }
}

// ---- LN apply + relu: h = relu((z-mu)*rstd*g + b); opt. buf_next = (1+eps')*h ----
template<bool FUSE_NEXT>
__global__ __launch_bounds__(256) void k_ln(
    const float* __restrict__ z, const float* __restrict__ red,
    const float* __restrict__ g, const float* __restrict__ b,
    float* __restrict__ hout, const float* __restrict__ eps_next,
    float* buf_next)
{
    const float mu = red[2], rstd = red[3];
    const int i = blockIdx.x * 256 + threadIdx.x;    // exactly NH/4 float4
    float4 v  = ((const float4*)z)[i];
    float4 gv = ((const float4*)g)[i & 31];
    float4 bv = ((const float4*)b)[i & 31];
    float4 o;
    o.x = fmaxf((v.x - mu) * rstd * gv.x + bv.x, 0.f);
    o.y = fmaxf((v.y - mu) * rstd * gv.y + bv.y, 0.f);
    o.z = fmaxf((v.z - mu) * rstd * gv.z + bv.z, 0.f);
    o.w = fmaxf((v.w - mu) * rstd * gv.w + bv.w, 0.f);
    ((float4*)hout)[i] = o;
    if constexpr (FUSE_NEXT) {
        const float a = 1.0f + eps_next[0];
        float4 s; s.x = a*o.x; s.y = a*o.y; s.z = a*o.z; s.w = a*o.w;
        ((float4*)buf_next)[i] = s;
    }
}

// ---- pack mlp_w1 [384][128] fp32 -> fragment-ordered bf16 [kb][nt][lane][8] ----
__global__ __launch_bounds__(256) void k_prep(
    const float* __restrict__ mw1, ushort* __restrict__ w1p)
{
    const int gidx = blockIdx.x * 256 + threadIdx.x;   // 0..6143
    const int lane = gidx & 63;
    const int ntkb = gidx >> 6;                        // 0..95
    const int nt = ntkb & 7, kb = ntkb >> 3;
    const int n  = nt * 16 + (lane & 15);
    const int k0 = kb * 32 + (lane >> 4) * 8;
    short8 v;
#pragma unroll
    for (int j = 0; j < 8; j++)
        v[j] = (short)f2b(mw1[(size_t)(k0 + j) * HID + n]);
    ((short8*)w1p)[gidx] = v;
}

// ---- final MLP via MFMA: logits = relu([h_src,h_dst,e] @ w1 + b1) @ w2 + b2 ----
__global__ __launch_bounds__(256) void k_mlp(
    const float* __restrict__ h, const int* __restrict__ ei,
    const float* __restrict__ ea, const float* __restrict__ eew,
    const float* __restrict__ eeb,
    const ushort* __restrict__ w1p, const float* __restrict__ b1,
    const float* __restrict__ w2, const float* __restrict__ b2,
    float* __restrict__ out)
{
    __shared__ ushort sU[64][392];              // 64 edges x 384 bf16, +8 pad = 50176 B
    const int* __restrict__ src = ei;
    const int* __restrict__ dst = ei + N_EDGES;
    const int tid = threadIdx.x;
    const int e0  = blockIdx.x * 64;

    // ---- stage gathered h[src]|h[dst] as bf16 (cols 0..255) ----
    const float4* h4 = (const float4*)h;
#pragma unroll
    for (int it = 0; it < 16; it++) {
        const int q  = it * 256 + tid;          // 0..4095
        const int e  = q >> 6;                  // wave-uniform
        const int c4 = q & 63;
        const int node = (c4 < 32) ? src[e0 + e] : dst[e0 + e];
        float4 v = h4[(size_t)node * 32 + (c4 & 31)];
        ushort4 u;
        u.x = f2b(v.x); u.y = f2b(v.y); u.z = f2b(v.z); u.w = f2b(v.w);
        *(ushort4*)&sU[e][c4 * 4] = u;
    }

    // ---- recompute edge features as bf16 (cols 256..383); ea loads wave-uniform ----
    {
        const int f = tid & 127;
        float wcol[EDGE_IN];
#pragma unroll
        for (int k = 0; k < EDGE_IN; k++) wcol[k] = eew[k * HID + f];
        const float bf = eeb[f];
#pragma unroll
        for (int it = 0; it < 32; it++) {
            const int e = it * 2 + (tid >> 7);  // wave-uniform
            const float4* ea4 = (const float4*)(ea + (size_t)(e0 + e) * EDGE_IN);
            float ev = bf;
#pragma unroll
            for (int k4 = 0; k4 < EDGE_IN / 4; k4++) {
                float4 v = ea4[k4];
                ev += v.x * wcol[k4*4] + v.y * wcol[k4*4+1] +
                      v.z * wcol[k4*4+2] + v.w * wcol[k4*4+3];
            }
            sU[e][256 + f] = f2b(ev);
        }
    }
    __syncthreads();

    // ---- MFMA: per wave, 16 edges x 128 hidden, K=384 ----
    const int lane = tid & 63;
    const int wv   = tid >> 6;                  // 0..3
    const int r0   = wv * 16;
    const int arow = r0 + (lane & 15);
    const int kgrp = lane >> 4;                 // 0..3
    f32x4 acc[8] = {};
    const short8* bfr = (const short8*)w1p;
    for (int kb = 0; kb < 12; kb++) {
        short8 afrag = *(const short8*)&sU[arow][kb * 32 + kgrp * 8];
#pragma unroll
        for (int nt = 0; nt < 8; nt++) {
            short8 bfrag = bfr[(kb * 8 + nt) * 64 + lane];
            acc[nt] = __builtin_amdgcn_mfma_f32_16x16x32_bf16(afrag, bfrag, acc[nt], 0, 0, 0);
        }
    }

    // ---- epilogue: relu(+b1) dot w2, reduce over hidden in-register ----
    float s0 = 0.f, s1 = 0.f, s2 = 0.f, s3 = 0.f;
#pragma unroll
    for (int nt = 0; nt < 8; nt++) {
        const int col = nt * 16 + (lane & 15);
        const float b1c = b1[col];
        const float w2c = w2[col];
        s0 += fmaxf(acc[nt][0] + b1c, 0.f) * w2c;
        s1 += fmaxf(acc[nt][1] + b1c, 0.f) * w2c;
        s2 += fmaxf(acc[nt][2] + b1c, 0.f) * w2c;
        s3 += fmaxf(acc[nt][3] + b1c, 0.f) * w2c;
    }
#pragma unroll
    for (int m = 1; m < 16; m <<= 1) {
        s0 += __shfl_xor(s0, m); s1 += __shfl_xor(s1, m);
        s2 += __shfl_xor(s2, m); s3 += __shfl_xor(s3, m);
    }
    if ((lane & 15) == 0) {
        const float bb = b2[0];
        const int eb = e0 + r0 + kgrp * 4;
        out[eb + 0] = s0 + bb; out[eb + 1] = s1 + bb;
        out[eb + 2] = s2 + bb; out[eb + 3] = s3 + bb;
    }
}

// ------------------------------------------------------------------
extern "C" void kernel_launch(void* const* d_in, const int* in_sizes, int n_in,
                              void* d_out, int out_size, void* d_ws, size_t ws_size,
                              hipStream_t stream)
{
    const float* x    = (const float*)d_in[0];
    const int*   ei   = (const int*)  d_in[1];
    const float* ea   = (const float*)d_in[2];
    const float* encw = (const float*)d_in[3];
    const float* encb = (const float*)d_in[4];
    const float* eew  = (const float*)d_in[5];
    const float* eeb  = (const float*)d_in[6];
    const float* gw1  = (const float*)d_in[7];
    const float* gb1  = (const float*)d_in[8];
    const float* gw2  = (const float*)d_in[9];
    const float* gb2  = (const float*)d_in[10];
    const float* geps = (const float*)d_in[11];
    const float* lng  = (const float*)d_in[12];
    const float* lnb  = (const float*)d_in[13];
    const float* mw1  = (const float*)d_in[14];
    const float* mb1  = (const float*)d_in[15];
    const float* mw2  = (const float*)d_in[16];
    const float* mb2  = (const float*)d_in[17];

    float* ws = (float*)d_ws;
    const size_t NH = (size_t)N_NODES * HID;    // 25,600,000 floats
    float* h    = ws;                           // node state
    float* buf  = ws + NH;                      // agg -> z1 -> z2 ; then w1p scratch
    float* red  = ws + 2 * NH;                  // [sum, sumsq, mu, rstd]
    // total d_ws usage: (2*NH + 4) * 4 bytes = 204,800,016 B

    k_node_enc<<<N_NODES / 16, 256, 0, stream>>>(x, encw, encb, h, geps, buf, red);

    const int ELEM_BLKS = (int)(NH / 4 / 256);  // 25000
    for (int l = 0; l < 3; l++) {
        k_msg<<<N_EDGES / 16, 256, 0, stream>>>(h, ei, ea, eew, eeb, buf);
        k_gemm<true, false><<<N_NODES / 64, 256, 0, stream>>>(
            buf, gw1 + (size_t)l * HID * HID, gb1 + (size_t)l * HID, buf, nullptr);
        k_gemm<false, true><<<N_NODES / 64, 256, 0, stream>>>(
            buf, gw2 + (size_t)l * HID * HID, gb2 + (size_t)l * HID, buf, red);
        k_lnfin<<<1, 64, 0, stream>>>(red);
        if (l < 2)
            k_ln<true><<<ELEM_BLKS, 256, 0, stream>>>(
                buf, red, lng + (size_t)l * HID, lnb + (size_t)l * HID, h,
                geps + l + 1, buf);
        else
            k_ln<false><<<ELEM_BLKS, 256, 0, stream>>>(
                buf, red, lng + (size_t)l * HID, lnb + (size_t)l * HID, h,
                nullptr, nullptr);
    }

    // buf is dead now; reuse it for the packed bf16 w1 fragments
    ushort* w1p = (ushort*)buf;
    k_prep<<<24, 256, 0, stream>>>(mw1, w1p);
    k_mlp<<<N_EDGES / 64, 256, 0, stream>>>(h, ei, ea, eew, eeb,
                                            w1p, mb1, mw2, mb2, (float*)d_out);
}

// Round 7
// 1601.566 us; speedup vs baseline: 1.7378x; 1.2181x over previous
//
#include <hip/hip_runtime.h>
#include <hip/hip_bf16.h>

#define N_NODES 200000
#define N_EDGES 600000
#define NODE_IN 32
#define EDGE_IN 16
#define HID     128
#define LN_EPS  1e-5f

typedef __attribute__((ext_vector_type(8))) short short8;   // 8 bf16 (4 VGPRs)
typedef __attribute__((ext_vector_type(4))) float f32x4;    // MFMA C/D frag

// fp32 -> bf16 round-to-nearest-even (finite values)
static __device__ __forceinline__ ushort f2b(float f) {
    unsigned u = __builtin_bit_cast(unsigned, f);
    unsigned r = (u + 0x7fffu + ((u >> 16) & 1u)) >> 16;
    return (ushort)r;
}
static __device__ __forceinline__ float b2f(ushort us) {
    unsigned u = ((unsigned)us) << 16;
    return __builtin_bit_cast(float, u);
}

// ---- pack 6 layer weights (gw1 x3, gw2 x3) 128x128 fp32 -> bf16 frags ----
// layout per matrix: [(kb*8+nt)*64 + lane] short8, B-frag n=nt*16+(lane&15),
// k0=kb*32+(lane>>4)*8  (same convention as verified round-6 k_prep)
__global__ __launch_bounds__(256) void k_prep_g(
    const float* __restrict__ gw1, const float* __restrict__ gw2,
    ushort* __restrict__ wpk)
{
    const int gidx = blockIdx.x * 256 + threadIdx.x;   // 0..12287
    const int m    = gidx >> 11;                       // matrix 0..5
    const int r    = gidx & 2047;
    const int lane = r & 63;
    const int ntkb = r >> 6;                           // 0..31
    const int nt = ntkb & 7, kb = ntkb >> 3;
    const int n  = nt * 16 + (lane & 15);
    const int k0 = kb * 32 + (lane >> 4) * 8;
    const float* W = (m < 3) ? gw1 + (size_t)m * HID * HID
                             : gw2 + (size_t)(m - 3) * HID * HID;
    short8 v;
#pragma unroll
    for (int j = 0; j < 8; j++)
        v[j] = (short)f2b(W[(size_t)(k0 + j) * HID + n]);
    ((short8*)wpk)[gidx] = v;
}

// ---- pack mlp_w1 [384][128] fp32 -> fragment-ordered bf16 ----
__global__ __launch_bounds__(256) void k_prep_m(
    const float* __restrict__ mw1, ushort* __restrict__ w1p)
{
    const int gidx = blockIdx.x * 256 + threadIdx.x;   // 0..6143
    const int lane = gidx & 63;
    const int ntkb = gidx >> 6;                        // 0..95
    const int nt = ntkb & 7, kb = ntkb >> 3;
    const int n  = nt * 16 + (lane & 15);
    const int k0 = kb * 32 + (lane >> 4) * 8;
    short8 v;
#pragma unroll
    for (int j = 0; j < 8; j++)
        v[j] = (short)f2b(mw1[(size_t)(k0 + j) * HID + n]);
    ((short8*)w1p)[gidx] = v;
}

// ---- node encoder: acc = x@enc_w+enc_b ; hb = bf16(acc); agg = (1+eps0)*acc ----
__global__ __launch_bounds__(256) void k_node_enc(
    const float* __restrict__ x, const float* __restrict__ w,
    const float* __restrict__ b, const float* __restrict__ epsp,
    ushort* __restrict__ hb, float* __restrict__ agg,
    float* __restrict__ red)
{
    __shared__ float sx[16][NODE_IN];           // 2 KB
    const int tid = threadIdx.x;
    const int n0  = blockIdx.x * 16;
    float* sxf = &sx[0][0];
    sxf[tid]       = x[(size_t)n0 * NODE_IN + tid];
    sxf[tid + 256] = x[(size_t)n0 * NODE_IN + tid + 256];

    const int f   = tid & 127;
    const int grp = tid >> 7;                   // 0..1
    float wcol[NODE_IN];
#pragma unroll
    for (int k = 0; k < NODE_IN; k++) wcol[k] = w[k * HID + f];
    const float bf = b[f];
    const float alpha = 1.0f + epsp[0];
    __syncthreads();

#pragma unroll
    for (int it = 0; it < 8; it++) {
        const int ln = it * 2 + grp;
        const int n  = n0 + ln;
        const float4* sx4 = (const float4*)sx[ln];
        float acc = bf;
#pragma unroll
        for (int k4 = 0; k4 < NODE_IN / 4; k4++) {
            float4 v = sx4[k4];
            acc += v.x * wcol[k4*4] + v.y * wcol[k4*4+1] +
                   v.z * wcol[k4*4+2] + v.w * wcol[k4*4+3];
        }
        hb[(size_t)n * HID + f]  = f2b(acc);
        agg[(size_t)n * HID + f] = alpha * acc;
    }
    if (blockIdx.x == 0 && tid == 0) { red[0] = 0.f; red[1] = 0.f; }
}

// ---- message + scatter: agg[dst] += relu(hb[src] + e), e recomputed ----
__global__ __launch_bounds__(256) void k_msg(
    const ushort* __restrict__ hb, const int* __restrict__ ei,
    const float* __restrict__ ea, const float* __restrict__ eew,
    const float* __restrict__ eeb, float* __restrict__ agg)
{
    __shared__ float sea[16][EDGE_IN];          // 1 KB
    const int* __restrict__ src = ei;
    const int* __restrict__ dst = ei + N_EDGES;
    const int tid = threadIdx.x;
    const int e0  = blockIdx.x * 16;
    ((float*)sea)[tid] = ea[(size_t)e0 * EDGE_IN + tid];   // 16 edges x 16 feats

    const int f   = tid & 127;
    const int grp = tid >> 7;
    float wcol[EDGE_IN];
#pragma unroll
    for (int k = 0; k < EDGE_IN; k++) wcol[k] = eew[k * HID + f];
    const float bf = eeb[f];
    __syncthreads();

#pragma unroll
    for (int it = 0; it < 8; it++) {
        const int le = it * 2 + grp;
        const int e  = e0 + le;
        const int s  = src[e];
        const int d  = dst[e];
        const float4* se4 = (const float4*)sea[le];
        float ev = bf;
#pragma unroll
        for (int k4 = 0; k4 < EDGE_IN / 4; k4++) {
            float4 v = se4[k4];
            ev += v.x * wcol[k4*4] + v.y * wcol[k4*4+1] +
                  v.z * wcol[k4*4+2] + v.w * wcol[k4*4+3];
        }
        float m = b2f(hb[(size_t)s * HID + f]) + ev;
        m = fmaxf(m, 0.f);
        atomicAdd(&agg[(size_t)d * HID + f], m);
    }
}

// -------- MFMA GEMM [Mx128]@[128x128]+bias -> bf16 out (IN-PLACE SAFE) --------
// IN_BF16: input is bf16 (else fp32). RELU_OUT: relu. REDUCE: sum/sumsq -> red.
template<bool IN_BF16, bool RELU_OUT, bool REDUCE>
__global__ __launch_bounds__(256) void k_gemm(
    const void* in_, const short8* __restrict__ wp,
    const float* __restrict__ bias, ushort* out, float* __restrict__ red)
{
    __shared__ ushort sU[64][136];              // 17408 B (pad 8 -> 2-way free)
    const int tid = threadIdx.x;
    const int m0  = blockIdx.x * 64;

    if constexpr (IN_BF16) {
        const short8* in8 = (const short8*)((const ushort*)in_ + (size_t)m0 * HID);
#pragma unroll
        for (int it = 0; it < 4; it++) {
            const int q = it * 256 + tid;       // 0..1023
            const int r = q >> 4, c8 = q & 15;
            *(short8*)&sU[r][c8 * 8] = in8[q];
        }
    } else {
        const float4* in4 = (const float4*)((const float*)in_ + (size_t)m0 * HID);
#pragma unroll
        for (int it = 0; it < 8; it++) {
            const int q = it * 256 + tid;       // 0..2047
            const int r = q >> 5, c4 = q & 31;
            float4 v = in4[q];
            ushort4 u;
            u.x = f2b(v.x); u.y = f2b(v.y); u.z = f2b(v.z); u.w = f2b(v.w);
            *(ushort4*)&sU[r][c4 * 4] = u;
        }
    }
    __syncthreads();

    const int lane = tid & 63;
    const int r0   = (tid >> 6) * 16;           // wave's 16 rows
    const int arow = r0 + (lane & 15);
    const int kg8  = (lane >> 4) * 8;
    f32x4 acc[8] = {};
    for (int kb = 0; kb < 4; kb++) {
        short8 af = *(const short8*)&sU[arow][kb * 32 + kg8];
#pragma unroll
        for (int nt = 0; nt < 8; nt++) {
            short8 bf8 = wp[(kb * 8 + nt) * 64 + lane];
            acc[nt] = __builtin_amdgcn_mfma_f32_16x16x32_bf16(af, bf8, acc[nt], 0, 0, 0);
        }
    }

    float lsum = 0.f, lsq = 0.f;
    const int rowb = m0 + r0 + (lane >> 4) * 4;
#pragma unroll
    for (int nt = 0; nt < 8; nt++) {
        const int c = nt * 16 + (lane & 15);
        const float bc = bias[c];
#pragma unroll
        for (int j = 0; j < 4; j++) {
            float o = acc[nt][j] + bc;
            if constexpr (RELU_OUT) o = fmaxf(o, 0.f);
            if constexpr (REDUCE) { lsum += o; lsq += o * o; }
            out[(size_t)(rowb + j) * HID + c] = f2b(o);
        }
    }

    if constexpr (REDUCE) {
#pragma unroll
        for (int off = 32; off; off >>= 1) {
            lsum += __shfl_down(lsum, off);
            lsq  += __shfl_down(lsq, off);
        }
        __shared__ float sws[4], swq[4];
        const int wid = tid >> 6;
        if ((tid & 63) == 0) { sws[wid] = lsum; swq[wid] = lsq; }
        __syncthreads();
        if (tid == 0) {
            atomicAdd(&red[0], sws[0] + sws[1] + sws[2] + sws[3]);
            atomicAdd(&red[1], swq[0] + swq[1] + swq[2] + swq[3]);
        }
    }
}

// ---- LN finalize: mu, rstd from sums; re-zero accumulators for next layer ----
__global__ void k_lnfin(float* __restrict__ red)
{
    if (threadIdx.x == 0) {
        const float inv = 1.0f / ((float)N_NODES * (float)HID);
        const float mu  = red[0] * inv;
        const float var = red[1] * inv - mu * mu;
        red[2] = mu;
        red[3] = 1.0f / sqrtf(var + LN_EPS);
        red[0] = 0.f; red[1] = 0.f;
    }
}

// ---- LN apply + relu: o = relu((zb-mu)*rstd*g+b); hb = bf16(o);
//      FUSE_NEXT: agg = (1+eps')*o (fp32 residual for next layer) ----
template<bool FUSE_NEXT>
__global__ __launch_bounds__(256) void k_ln(
    const ushort* __restrict__ zb, const float* __restrict__ red,
    const float* __restrict__ g, const float* __restrict__ b,
    ushort* __restrict__ hb, const float* __restrict__ eps_next,
    float* __restrict__ agg)
{
    const float mu = red[2], rstd = red[3];
    const int i = blockIdx.x * 256 + threadIdx.x;    // 0..NH/8-1
    short8 z8 = ((const short8*)zb)[i];
    const int cb = (i & 15) * 2;                     // float4 idx into g/b
    float4 g0 = ((const float4*)g)[cb],  g1 = ((const float4*)g)[cb + 1];
    float4 b0 = ((const float4*)b)[cb],  b1 = ((const float4*)b)[cb + 1];
    float o[8];
    o[0] = fmaxf((b2f((ushort)z8[0]) - mu) * rstd * g0.x + b0.x, 0.f);
    o[1] = fmaxf((b2f((ushort)z8[1]) - mu) * rstd * g0.y + b0.y, 0.f);
    o[2] = fmaxf((b2f((ushort)z8[2]) - mu) * rstd * g0.z + b0.z, 0.f);
    o[3] = fmaxf((b2f((ushort)z8[3]) - mu) * rstd * g0.w + b0.w, 0.f);
    o[4] = fmaxf((b2f((ushort)z8[4]) - mu) * rstd * g1.x + b1.x, 0.f);
    o[5] = fmaxf((b2f((ushort)z8[5]) - mu) * rstd * g1.y + b1.y, 0.f);
    o[6] = fmaxf((b2f((ushort)z8[6]) - mu) * rstd * g1.z + b1.z, 0.f);
    o[7] = fmaxf((b2f((ushort)z8[7]) - mu) * rstd * g1.w + b1.w, 0.f);
    short8 h8;
#pragma unroll
    for (int j = 0; j < 8; j++) h8[j] = (short)f2b(o[j]);
    ((short8*)hb)[i] = h8;
    if constexpr (FUSE_NEXT) {
        const float a = 1.0f + eps_next[0];
        float4 A0, A1;
        A0.x = a*o[0]; A0.y = a*o[1]; A0.z = a*o[2]; A0.w = a*o[3];
        A1.x = a*o[4]; A1.y = a*o[5]; A1.z = a*o[6]; A1.w = a*o[7];
        ((float4*)agg)[i * 2]     = A0;
        ((float4*)agg)[i * 2 + 1] = A1;
    }
}

// ---- final MLP via MFMA: logits = relu([hb_src,hb_dst,e] @ w1 + b1) @ w2 + b2 ----
__global__ __launch_bounds__(256) void k_mlp(
    const ushort* __restrict__ hb, const int* __restrict__ ei,
    const float* __restrict__ ea, const float* __restrict__ eew,
    const float* __restrict__ eeb,
    const ushort* __restrict__ w1p, const float* __restrict__ b1,
    const float* __restrict__ w2, const float* __restrict__ b2,
    float* __restrict__ out)
{
    __shared__ ushort sU[64][392];              // 64 edges x 384 bf16, +8 pad
    const int* __restrict__ src = ei;
    const int* __restrict__ dst = ei + N_EDGES;
    const int tid = threadIdx.x;
    const int e0  = blockIdx.x * 64;

    // ---- stage gathered hb[src]|hb[dst] (cols 0..255), 16 B chunks ----
    const short8* hb8 = (const short8*)hb;      // node row = 16 short8
#pragma unroll
    for (int it = 0; it < 8; it++) {
        const int q = it * 256 + tid;           // 0..2047
        const int e = q >> 5;                   // wave-uniform
        const int c = q & 31;                   // 0..31 (16 src + 16 dst chunks)
        const int node = (c < 16) ? src[e0 + e] : dst[e0 + e];
        short8 v = hb8[(size_t)node * 16 + (c & 15)];
        *(short8*)&sU[e][c * 8] = v;
    }

    // ---- recompute edge features as bf16 (cols 256..383) ----
    {
        const int f = tid & 127;
        float wcol[EDGE_IN];
#pragma unroll
        for (int k = 0; k < EDGE_IN; k++) wcol[k] = eew[k * HID + f];
        const float bf = eeb[f];
#pragma unroll
        for (int it = 0; it < 32; it++) {
            const int e = it * 2 + (tid >> 7);  // wave-uniform
            const float4* ea4 = (const float4*)(ea + (size_t)(e0 + e) * EDGE_IN);
            float ev = bf;
#pragma unroll
            for (int k4 = 0; k4 < EDGE_IN / 4; k4++) {
                float4 v = ea4[k4];
                ev += v.x * wcol[k4*4] + v.y * wcol[k4*4+1] +
                      v.z * wcol[k4*4+2] + v.w * wcol[k4*4+3];
            }
            sU[e][256 + f] = f2b(ev);
        }
    }
    __syncthreads();

    // ---- MFMA: per wave, 16 edges x 128 hidden, K=384 ----
    const int lane = tid & 63;
    const int wv   = tid >> 6;                  // 0..3
    const int r0   = wv * 16;
    const int arow = r0 + (lane & 15);
    const int kgrp = lane >> 4;                 // 0..3
    f32x4 acc[8] = {};
    const short8* bfr = (const short8*)w1p;
    for (int kb = 0; kb < 12; kb++) {
        short8 afrag = *(const short8*)&sU[arow][kb * 32 + kgrp * 8];
#pragma unroll
        for (int nt = 0; nt < 8; nt++) {
            short8 bfrag = bfr[(kb * 8 + nt) * 64 + lane];
            acc[nt] = __builtin_amdgcn_mfma_f32_16x16x32_bf16(afrag, bfrag, acc[nt], 0, 0, 0);
        }
    }

    // ---- epilogue: relu(+b1) dot w2, reduce over hidden in-register ----
    float s0 = 0.f, s1 = 0.f, s2 = 0.f, s3 = 0.f;
#pragma unroll
    for (int nt = 0; nt < 8; nt++) {
        const int col = nt * 16 + (lane & 15);
        const float b1c = b1[col];
        const float w2c = w2[col];
        s0 += fmaxf(acc[nt][0] + b1c, 0.f) * w2c;
        s1 += fmaxf(acc[nt][1] + b1c, 0.f) * w2c;
        s2 += fmaxf(acc[nt][2] + b1c, 0.f) * w2c;
        s3 += fmaxf(acc[nt][3] + b1c, 0.f) * w2c;
    }
#pragma unroll
    for (int m = 1; m < 16; m <<= 1) {
        s0 += __shfl_xor(s0, m); s1 += __shfl_xor(s1, m);
        s2 += __shfl_xor(s2, m); s3 += __shfl_xor(s3, m);
    }
    if ((lane & 15) == 0) {
        const float bb = b2[0];
        const int eb = e0 + r0 + kgrp * 4;
        out[eb + 0] = s0 + bb; out[eb + 1] = s1 + bb;
        out[eb + 2] = s2 + bb; out[eb + 3] = s3 + bb;
    }
}

// ------------------------------------------------------------------
extern "C" void kernel_launch(void* const* d_in, const int* in_sizes, int n_in,
                              void* d_out, int out_size, void* d_ws, size_t ws_size,
                              hipStream_t stream)
{
    const float* x    = (const float*)d_in[0];
    const int*   ei   = (const int*)  d_in[1];
    const float* ea   = (const float*)d_in[2];
    const float* encw = (const float*)d_in[3];
    const float* encb = (const float*)d_in[4];
    const float* eew  = (const float*)d_in[5];
    const float* eeb  = (const float*)d_in[6];
    const float* gw1  = (const float*)d_in[7];
    const float* gb1  = (const float*)d_in[8];
    const float* gw2  = (const float*)d_in[9];
    const float* gb2  = (const float*)d_in[10];
    const float* geps = (const float*)d_in[11];
    const float* lng  = (const float*)d_in[12];
    const float* lnb  = (const float*)d_in[13];
    const float* mw1  = (const float*)d_in[14];
    const float* mb1  = (const float*)d_in[15];
    const float* mw2  = (const float*)d_in[16];
    const float* mb2  = (const float*)d_in[17];

    float* ws = (float*)d_ws;
    const size_t NH = (size_t)N_NODES * HID;    // 25,600,000
    float*  agg = ws;                           // fp32 [NH]: residual + atomics
    ushort* zb  = (ushort*)(ws + NH);           // bf16 [NH]: z1 -> z2 (in-place)
    ushort* hb  = (ushort*)(ws + NH + NH / 2);  // bf16 [NH]: node state (gathers)
    float*  red = ws + 2 * NH;                  // [sum, sumsq, mu, rstd]
    // total d_ws usage: (2*NH + 4) * 4 B = 204,800,016 B (round-3 proven)

    // packed layer weights live in d_out scratch (overwritten by k_mlp at the end)
    ushort* wpk = (ushort*)d_out;               // 6 x 32 KB = 192 KB

    k_prep_g<<<48, 256, 0, stream>>>(gw1, gw2, wpk);
    k_node_enc<<<N_NODES / 16, 256, 0, stream>>>(x, encw, encb, geps, hb, agg, red);

    const int LN_BLKS = (int)(NH / 8 / 256);    // 12500
    for (int l = 0; l < 3; l++) {
        k_msg<<<N_EDGES / 16, 256, 0, stream>>>(hb, ei, ea, eew, eeb, agg);
        k_gemm<false, true, false><<<N_NODES / 64, 256, 0, stream>>>(
            agg, (const short8*)wpk + (size_t)l * 2048,
            gb1 + (size_t)l * HID, zb, nullptr);
        k_gemm<true, false, true><<<N_NODES / 64, 256, 0, stream>>>(
            zb, (const short8*)wpk + (size_t)(3 + l) * 2048,
            gb2 + (size_t)l * HID, zb, red);
        k_lnfin<<<1, 64, 0, stream>>>(red);
        if (l < 2)
            k_ln<true><<<LN_BLKS, 256, 0, stream>>>(
                zb, red, lng + (size_t)l * HID, lnb + (size_t)l * HID, hb,
                geps + l + 1, agg);
        else
            k_ln<false><<<LN_BLKS, 256, 0, stream>>>(
                zb, red, lng + (size_t)l * HID, lnb + (size_t)l * HID, hb,
                nullptr, nullptr);
    }

    // agg is dead now; reuse it for the packed bf16 mlp_w1 fragments
    ushort* w1p = (ushort*)agg;
    k_prep_m<<<24, 256, 0, stream>>>(mw1, w1p);
    k_mlp<<<N_EDGES / 64, 256, 0, stream>>>(hb, ei, ea, eew, eeb,
                                            w1p, mb1, mw2, mb2, (float*)d_out);
}